// Round 6
// baseline (1202.210 us; speedup 1.0000x reference)
//
#include <hip/hip_runtime.h>
#include <hip/hip_bf16.h>
#include <string.h>

#define NNODE 50000
#define NEDGE 1600000
#define INF   256
#define OUTF  32
#define NH    4
#define EF    64
#define NET   5

typedef unsigned short u16t;
typedef unsigned char  u8t;

__device__ __forceinline__ float b2f(u16t u) {
    union { unsigned int i; float f; } v; v.i = ((unsigned int)u) << 16; return v.f;
}
__device__ __forceinline__ u16t f2b(float f) {
    __hip_bfloat16 h = __float2bfloat16(f);
    u16t u; memcpy(&u, &h, 2); return u;
}
__device__ __forceinline__ int clampi(int x, int lo, int hi) {
    return x < lo ? lo : (x > hi ? hi : x);
}

// ---------------------------------------------------------------------------
// k_detect: int64-vs-int32 layout sniff (odd words all zero => int64).
// ---------------------------------------------------------------------------
__global__ void k_detect(const int* __restrict__ el, const int* __restrict__ ety,
                         int* __restrict__ flag) {
    int tid = threadIdx.x;
    int w = tid >> 6, lane = tid & 63;
    const int* p = (w == 0) ? el : ety;
    int x = p[2 * lane + 1];
    unsigned long long b = __ballot(x != 0);
    if (lane == 0) flag[w] = (b == 0ULL) ? 1 : 0;
}

// ---------------------------------------------------------------------------
// k_prep: fold a_l/a_r into W -> wl/wr [256][4]; h_e [5][4] from folded W_e.
// ---------------------------------------------------------------------------
__global__ void k_prep(const float* __restrict__ W, const float* __restrict__ We,
                       const float* __restrict__ emb, const float* __restrict__ al,
                       const float* __restrict__ ar, const float* __restrict__ ae,
                       float* __restrict__ wl, float* __restrict__ wr,
                       float* __restrict__ he) {
    __shared__ float wes[EF * NH];
    int tid = threadIdx.x;
    {
        int k = tid;  // 0..255
        for (int h = 0; h < NH; h++) {
            float accl = 0.f, accr = 0.f;
            for (int d = 0; d < OUTF; d++) {
                float w = W[k * (NH * OUTF) + h * OUTF + d];
                accl += w * al[h * OUTF + d];
                accr += w * ar[h * OUTF + d];
            }
            wl[k * NH + h] = accl;
            wr[k * NH + h] = accr;
        }
    }
    if (tid < EF) {
        int k = tid;
        for (int h = 0; h < NH; h++) {
            float s = 0.f;
            for (int d = 0; d < EF; d++)
                s += We[k * (NH * EF) + h * EF + d] * ae[h * EF + d];
            wes[k * NH + h] = s;
        }
    }
    __syncthreads();
    if (tid < NET * NH) {
        int t = tid / NH, h = tid % NH;
        float s = 0.f;
        for (int k = 0; k < EF; k++)
            s += emb[t * EF + k] * wes[k * NH + h];
        he[tid] = s;
    }
}

// ---------------------------------------------------------------------------
// k_rowdot: out[row][0..3] = X[row,:] @ wvec; one wave per row.
// ---------------------------------------------------------------------------
__global__ void k_rowdot(const float* __restrict__ X, const float* __restrict__ wvec,
                         float* __restrict__ out) {
    __shared__ float w[INF * NH];
    int tid = threadIdx.x;
    ((float4*)w)[tid] = ((const float4*)wvec)[tid];
    __syncthreads();
    int wave = tid >> 6, lane = tid & 63;
    int row = blockIdx.x * 4 + wave;
    float4 xv = *(const float4*)(X + (size_t)row * INF + lane * 4);
    float xs[4] = {xv.x, xv.y, xv.z, xv.w};
    float4 acc = {0.f, 0.f, 0.f, 0.f};
#pragma unroll
    for (int j = 0; j < 4; j++) {
        float xf = xs[j];
        float4 wv = ((float4*)w)[lane * 4 + j];
        acc.x += xf * wv.x; acc.y += xf * wv.y;
        acc.z += xf * wv.z; acc.w += xf * wv.w;
    }
#pragma unroll
    for (int off = 32; off > 0; off >>= 1) {
        acc.x += __shfl_xor(acc.x, off);
        acc.y += __shfl_xor(acc.y, off);
        acc.z += __shfl_xor(acc.z, off);
        acc.w += __shfl_xor(acc.w, off);
    }
    if (lane == 0) ((float4*)out)[row] = acc;
}

// ---------------------------------------------------------------------------
// k_gemm: htail[row][c] = tail[row,:] @ W[:,c], fp32 in/accum, bf16 store.
// ---------------------------------------------------------------------------
__global__ void k_gemm(const float* __restrict__ X, const float* __restrict__ W,
                       u16t* __restrict__ H) {
    __shared__ float xs[16 * INF];
    int tid = threadIdx.x;
    int rowbase = blockIdx.x * 16;
    const float4* Xv = (const float4*)(X + (size_t)rowbase * INF);
    for (int i = tid; i < 16 * INF / 4; i += 256)
        ((float4*)xs)[i] = Xv[i];
    __syncthreads();
    int cg = tid & 15, r = tid >> 4;
    int c0 = cg * 8;
    float acc[8];
#pragma unroll
    for (int i = 0; i < 8; i++) acc[i] = 0.f;
    const float* Wp = W + c0;
    const float* xr = xs + r * INF;
#pragma unroll 4
    for (int k = 0; k < INF; k++) {
        float xv = xr[k];
        float4 w0 = *(const float4*)(Wp + k * 128);
        float4 w1 = *(const float4*)(Wp + k * 128 + 4);
        acc[0] += xv * w0.x; acc[1] += xv * w0.y;
        acc[2] += xv * w0.z; acc[3] += xv * w0.w;
        acc[4] += xv * w1.x; acc[5] += xv * w1.y;
        acc[6] += xv * w1.z; acc[7] += xv * w1.w;
    }
    u16t* Hp = H + (size_t)(rowbase + r) * 128 + c0;
    ushort4 oa = {f2b(acc[0]), f2b(acc[1]), f2b(acc[2]), f2b(acc[3])};
    ushort4 ob = {f2b(acc[4]), f2b(acc[5]), f2b(acc[6]), f2b(acc[7])};
    *(ushort4*)(Hp) = oa;
    *(ushort4*)(Hp + 4) = ob;
}

// ---------------------------------------------------------------------------
// k_edge: per edge: ex = exp(lrelu(att)); atomic den[hi][h] += ex; count[hi]++
// ---------------------------------------------------------------------------
__global__ void k_edge(const int* __restrict__ el, const int* __restrict__ ety,
                       const int* __restrict__ flag,
                       const float* __restrict__ hl, const float* __restrict__ hr,
                       const float* __restrict__ heg,
                       float* __restrict__ den, int* __restrict__ count) {
    __shared__ float hes[NET * NH];
    int tid = threadIdx.x;
    if (tid < NET * NH) hes[tid] = heg[tid];
    __syncthreads();
    int wf = flag[0], wt = flag[1];
    int e = blockIdx.x * 256 + tid;
    int hi = wf ? el[2 * (long long)e]           : el[e];
    int ti = wf ? el[2 * ((long long)NEDGE + e)] : el[NEDGE + e];
    int ty = wt ? ety[2 * (long long)e]          : ety[e];
    hi = clampi(hi, 0, NNODE - 1);
    ti = clampi(ti, 0, NNODE - 1);
    ty = clampi(ty, 0, NET - 1);
    float4 l = ((const float4*)hl)[hi];
    float4 r = ((const float4*)hr)[ti];
    float v0 = l.x + r.x + hes[ty * 4 + 0];
    float v1 = l.y + r.y + hes[ty * 4 + 1];
    float v2 = l.z + r.z + hes[ty * 4 + 2];
    float v3 = l.w + r.w + hes[ty * 4 + 3];
    v0 = fminf(v0 > 0.f ? v0 : 0.2f * v0, 80.f);
    v1 = fminf(v1 > 0.f ? v1 : 0.2f * v1, 80.f);
    v2 = fminf(v2 > 0.f ? v2 : 0.2f * v2, 80.f);
    v3 = fminf(v3 > 0.f ? v3 : 0.2f * v3, 80.f);
    atomicAdd(&den[hi * 4 + 0], __expf(v0));
    atomicAdd(&den[hi * 4 + 1], __expf(v1));
    atomicAdd(&den[hi * 4 + 2], __expf(v2));
    atomicAdd(&den[hi * 4 + 3], __expf(v3));
    atomicAdd(&count[hi], 1);
}

// ---------------------------------------------------------------------------
// k_scan: exclusive prefix sum, 256 threads, two-phase.
// ---------------------------------------------------------------------------
__global__ void k_scan(const int* __restrict__ count, int* __restrict__ row_start,
                       int* __restrict__ cursor) {
    __shared__ int sums[256];
    const int CH = 196;  // 256*196 = 50176 >= 50000
    int tid = threadIdx.x;
    int base = tid * CH;
    int s = 0;
    for (int i = 0; i < CH; i++) {
        int idx = base + i;
        if (idx < NNODE) s += count[idx];
    }
    sums[tid] = s;
    __syncthreads();
    for (int off = 1; off < 256; off <<= 1) {
        int v = (tid >= off) ? sums[tid - off] : 0;
        __syncthreads();
        sums[tid] += v;
        __syncthreads();
    }
    int run = tid ? sums[tid - 1] : 0;
    for (int i = 0; i < CH; i++) {
        int idx = base + i;
        if (idx < NNODE) {
            row_start[idx] = run;
            cursor[idx] = run;
            run += count[idx];
        }
    }
    if (tid == 255) row_start[NNODE] = sums[255];
}

// ---------------------------------------------------------------------------
// k_scatter: CSR fill — tail id (u16) + edge type (u8), bounds-checked.
// ---------------------------------------------------------------------------
__global__ void k_scatter(const int* __restrict__ el, const int* __restrict__ ety,
                          const int* __restrict__ flag, int* __restrict__ cursor,
                          u16t* __restrict__ ctail, u8t* __restrict__ cty) {
    int wf = flag[0], wt = flag[1];
    int e = blockIdx.x * 256 + threadIdx.x;
    int hi = wf ? el[2 * (long long)e]           : el[e];
    int ti = wf ? el[2 * ((long long)NEDGE + e)] : el[NEDGE + e];
    int ty = wt ? ety[2 * (long long)e]          : ety[e];
    hi = clampi(hi, 0, NNODE - 1);
    ti = clampi(ti, 0, NNODE - 1);
    ty = clampi(ty, 0, NET - 1);
    int pos = atomicAdd(&cursor[hi], 1);
    if (pos >= 0 && pos < NEDGE) {
        ctail[pos] = (u16t)ti;
        cty[pos]   = (u8t)ty;
    }
}

// ---------------------------------------------------------------------------
// k_agg: wave per head node; recompute ex per CSR edge; gather htail bf16;
// out = elu(acc/den), f32 pair store.
// ---------------------------------------------------------------------------
__global__ void k_agg(const int* __restrict__ rs, const u16t* __restrict__ ctail,
                      const u8t* __restrict__ cty, const float* __restrict__ hl,
                      const float* __restrict__ hr, const float* __restrict__ heg,
                      const float* __restrict__ den, const u16t* __restrict__ ht,
                      float2* __restrict__ out) {
    __shared__ float hes[NET * NH];
    int tid = threadIdx.x;
    if (tid < NET * NH) hes[tid] = heg[tid];
    __syncthreads();
    int wave = tid >> 6, lane = tid & 63;
    int node = blockIdx.x * 4 + wave;
    int start = rs[node], end = rs[node + 1];
    start = clampi(start, 0, NEDGE);
    end   = clampi(end, start, NEDGE);
    int h = lane >> 4;
    float hlv = hl[node * 4 + h];
    float dv  = den[node * 4 + h];
    float a0 = 0.f, a1 = 0.f;
    for (int j = start; j < end; j++) {
        int ti = clampi((int)ctail[j], 0, NNODE - 1);
        int ty = clampi((int)cty[j], 0, NET - 1);
        float att = hlv + hr[ti * 4 + h] + hes[ty * 4 + h];
        att = fminf(att > 0.f ? att : 0.2f * att, 80.f);
        float exv = __expf(att);
        unsigned int hv = *(const unsigned int*)(ht + (size_t)ti * 128 + lane * 2);
        a0 += exv * b2f((u16t)(hv & 0xffff));
        a1 += exv * b2f((u16t)(hv >> 16));
    }
    float o0 = 0.f, o1 = 0.f;
    if (dv > 0.f) { o0 = a0 / dv; o1 = a1 / dv; }
    o0 = o0 > 0.f ? o0 : expm1f(o0);
    o1 = o1 > 0.f ? o1 : expm1f(o1);
    float2 ov = {o0, o1};
    out[(size_t)node * 64 + lane] = ov;
}

// ---------------------------------------------------------------------------
// k_alpha: recompute ex per edge, alpha = ex/den[hi], f32 store (overwrites
// the htail scratch region — runs after k_agg).
// ---------------------------------------------------------------------------
__global__ void k_alpha(const int* __restrict__ el, const int* __restrict__ ety,
                        const int* __restrict__ flag,
                        const float* __restrict__ hl, const float* __restrict__ hr,
                        const float* __restrict__ heg, const float* __restrict__ den,
                        float* __restrict__ alpha) {
    __shared__ float hes[NET * NH];
    int tid = threadIdx.x;
    if (tid < NET * NH) hes[tid] = heg[tid];
    __syncthreads();
    int wf = flag[0], wt = flag[1];
    int e = blockIdx.x * 256 + tid;
    int hi = wf ? el[2 * (long long)e]           : el[e];
    int ti = wf ? el[2 * ((long long)NEDGE + e)] : el[NEDGE + e];
    int ty = wt ? ety[2 * (long long)e]          : ety[e];
    hi = clampi(hi, 0, NNODE - 1);
    ti = clampi(ti, 0, NNODE - 1);
    ty = clampi(ty, 0, NET - 1);
    float4 l = ((const float4*)hl)[hi];
    float4 r = ((const float4*)hr)[ti];
    float4 d = ((const float4*)den)[hi];
    float v0 = l.x + r.x + hes[ty * 4 + 0];
    float v1 = l.y + r.y + hes[ty * 4 + 1];
    float v2 = l.z + r.z + hes[ty * 4 + 2];
    float v3 = l.w + r.w + hes[ty * 4 + 3];
    v0 = fminf(v0 > 0.f ? v0 : 0.2f * v0, 80.f);
    v1 = fminf(v1 > 0.f ? v1 : 0.2f * v1, 80.f);
    v2 = fminf(v2 > 0.f ? v2 : 0.2f * v2, 80.f);
    v3 = fminf(v3 > 0.f ? v3 : 0.2f * v3, 80.f);
    float4 o;
    o.x = d.x > 0.f ? __expf(v0) / d.x : 0.f;
    o.y = d.y > 0.f ? __expf(v1) / d.y : 0.f;
    o.z = d.z > 0.f ? __expf(v2) / d.z : 0.f;
    o.w = d.w > 0.f ? __expf(v3) / d.w : 0.f;
    ((float4*)alpha)[e] = o;
}

// ---------------------------------------------------------------------------
extern "C" void kernel_launch(void* const* d_in, const int* in_sizes, int n_in,
                              void* d_out, int out_size, void* d_ws, size_t ws_size,
                              hipStream_t stream) {
    const float* head = (const float*)d_in[0];
    const float* tail = (const float*)d_in[1];
    const float* W    = (const float*)d_in[2];
    const float* We   = (const float*)d_in[3];
    const float* emb  = (const float*)d_in[4];
    const float* al   = (const float*)d_in[5];
    const float* ar   = (const float*)d_in[6];
    const float* ae   = (const float*)d_in[7];
    const int*   el   = (const int*)d_in[8];
    const int*   ety  = (const int*)d_in[9];

    float* ws = (float*)d_ws;
    // compact layout: 1,952,100 f32 slots = 7.45 MiB total
    float* hl       = ws;                       // 200,000
    float* hr       = ws + 200000;              // 200,000
    float* wl       = ws + 400000;              // 1,024
    float* wr       = ws + 401024;              // 1,024
    float* heg      = ws + 402048;              // 32
    int*   flag     = (int*)(ws + 402080);      // 16
    float* den      = ws + 402096;              // 200,000 } contiguous,
    int*   count    = (int*)(ws + 602096);      // 50,000  } one memset
    int*   cursor   = (int*)(ws + 652096);      // 50,000
    int*   row_start= (int*)(ws + 702096);      // 50,001 (+3 pad)
    u16t*  ctail    = (u16t*)(ws + 752100);     // 1.6M u16
    u8t*   cty      = (u8t*)(ws + 1552100);     // 1.6M u8

    // d_out: f32 out [50000,128] then f32 alpha [E,4]
    float* outp   = (float*)d_out;              // 6,400,000 f32
    float* alphap = (float*)d_out + 6400000;    // 6,400,000 f32
    // htail bf16 scratch parked in the alpha region (12.8 MB of its 25.6 MB);
    // k_agg consumes it before k_alpha overwrites the region.
    u16t* htail = (u16t*)alphap;

    (void)hipMemsetAsync(den, 0, 250000 * sizeof(int), stream);  // den + count

    k_detect<<<1, 128, 0, stream>>>(el, ety, flag);
    k_prep<<<1, 256, 0, stream>>>(W, We, emb, al, ar, ae, wl, wr, heg);
    k_rowdot<<<NNODE / 4, 256, 0, stream>>>(head, wl, hl);
    k_rowdot<<<NNODE / 4, 256, 0, stream>>>(tail, wr, hr);
    k_gemm<<<NNODE / 16, 256, 0, stream>>>(tail, W, htail);
    k_edge<<<NEDGE / 256, 256, 0, stream>>>(el, ety, flag, hl, hr, heg, den, count);
    k_scan<<<1, 256, 0, stream>>>(count, row_start, cursor);
    k_scatter<<<NEDGE / 256, 256, 0, stream>>>(el, ety, flag, cursor, ctail, cty);
    k_agg<<<NNODE / 4, 256, 0, stream>>>(row_start, ctail, cty, hl, hr, heg, den,
                                         htail, (float2*)outp);
    k_alpha<<<NEDGE / 256, 256, 0, stream>>>(el, ety, flag, hl, hr, heg, den, alphap);
}

// Round 7
// 774.692 us; speedup vs baseline: 1.5519x; 1.5519x over previous
//
#include <hip/hip_runtime.h>
#include <hip/hip_bf16.h>
#include <string.h>

#define NNODE 50000
#define NEDGE 1600000
#define INF   256
#define OUTF  32
#define NH    4
#define EF    64
#define NET   5

typedef unsigned short u16t;

__device__ __forceinline__ float b2f(u16t u) {
    union { unsigned int i; float f; } v; v.i = ((unsigned int)u) << 16; return v.f;
}
__device__ __forceinline__ u16t f2b(float f) {
    __hip_bfloat16 h = __float2bfloat16(f);
    u16t u; memcpy(&u, &h, 2); return u;
}

// ---------------------------------------------------------------------------
// k_detect: int64-vs-int32 layout sniff (odd words all zero => int64).
// ---------------------------------------------------------------------------
__global__ void k_detect(const int* __restrict__ el, const int* __restrict__ ety,
                         int* __restrict__ flag) {
    int tid = threadIdx.x;
    int w = tid >> 6, lane = tid & 63;
    const int* p = (w == 0) ? el : ety;
    int x = p[2 * lane + 1];
    unsigned long long b = __ballot(x != 0);
    if (lane == 0) flag[w] = (b == 0ULL) ? 1 : 0;
}

// ---------------------------------------------------------------------------
// k_prep: fold a_l/a_r into W -> wl/wr [256][4]; h_e [5][4] from folded W_e.
// ---------------------------------------------------------------------------
__global__ void k_prep(const float* __restrict__ W, const float* __restrict__ We,
                       const float* __restrict__ emb, const float* __restrict__ al,
                       const float* __restrict__ ar, const float* __restrict__ ae,
                       float* __restrict__ wl, float* __restrict__ wr,
                       float* __restrict__ he) {
    __shared__ float wes[EF * NH];
    int tid = threadIdx.x;
    {
        int k = tid;  // 0..255
        for (int h = 0; h < NH; h++) {
            float accl = 0.f, accr = 0.f;
            for (int d = 0; d < OUTF; d++) {
                float w = W[k * (NH * OUTF) + h * OUTF + d];
                accl += w * al[h * OUTF + d];
                accr += w * ar[h * OUTF + d];
            }
            wl[k * NH + h] = accl;
            wr[k * NH + h] = accr;
        }
    }
    if (tid < EF) {
        int k = tid;
        for (int h = 0; h < NH; h++) {
            float s = 0.f;
            for (int d = 0; d < EF; d++)
                s += We[k * (NH * EF) + h * EF + d] * ae[h * EF + d];
            wes[k * NH + h] = s;
        }
    }
    __syncthreads();
    if (tid < NET * NH) {
        int t = tid / NH, h = tid % NH;
        float s = 0.f;
        for (int k = 0; k < EF; k++)
            s += emb[t * EF + k] * wes[k * NH + h];
        he[tid] = s;
    }
}

// ---------------------------------------------------------------------------
// k_rowdot: out[row][0..3] = X[row,:] @ wvec; one wave per row.
// ---------------------------------------------------------------------------
__global__ void k_rowdot(const float* __restrict__ X, const float* __restrict__ wvec,
                         float* __restrict__ out) {
    __shared__ float w[INF * NH];
    int tid = threadIdx.x;
    ((float4*)w)[tid] = ((const float4*)wvec)[tid];
    __syncthreads();
    int wave = tid >> 6, lane = tid & 63;
    int row = blockIdx.x * 4 + wave;
    float4 xv = *(const float4*)(X + (size_t)row * INF + lane * 4);
    float xs[4] = {xv.x, xv.y, xv.z, xv.w};
    float4 acc = {0.f, 0.f, 0.f, 0.f};
#pragma unroll
    for (int j = 0; j < 4; j++) {
        float xf = xs[j];
        float4 wv = ((float4*)w)[lane * 4 + j];
        acc.x += xf * wv.x; acc.y += xf * wv.y;
        acc.z += xf * wv.z; acc.w += xf * wv.w;
    }
#pragma unroll
    for (int off = 32; off > 0; off >>= 1) {
        acc.x += __shfl_xor(acc.x, off);
        acc.y += __shfl_xor(acc.y, off);
        acc.z += __shfl_xor(acc.z, off);
        acc.w += __shfl_xor(acc.w, off);
    }
    if (lane == 0) ((float4*)out)[row] = acc;
}

// ---------------------------------------------------------------------------
// k_gemm: htail[row][c] = tail[row,:] @ W[:,c], fp32 in/accum, bf16 store.
// ---------------------------------------------------------------------------
__global__ void k_gemm(const float* __restrict__ X, const float* __restrict__ W,
                       u16t* __restrict__ H) {
    __shared__ float xs[16 * INF];
    int tid = threadIdx.x;
    int rowbase = blockIdx.x * 16;
    const float4* Xv = (const float4*)(X + (size_t)rowbase * INF);
    for (int i = tid; i < 16 * INF / 4; i += 256)
        ((float4*)xs)[i] = Xv[i];
    __syncthreads();
    int cg = tid & 15, r = tid >> 4;
    int c0 = cg * 8;
    float acc[8];
#pragma unroll
    for (int i = 0; i < 8; i++) acc[i] = 0.f;
    const float* Wp = W + c0;
    const float* xr = xs + r * INF;
#pragma unroll 4
    for (int k = 0; k < INF; k++) {
        float xv = xr[k];
        float4 w0 = *(const float4*)(Wp + k * 128);
        float4 w1 = *(const float4*)(Wp + k * 128 + 4);
        acc[0] += xv * w0.x; acc[1] += xv * w0.y;
        acc[2] += xv * w0.z; acc[3] += xv * w0.w;
        acc[4] += xv * w1.x; acc[5] += xv * w1.y;
        acc[6] += xv * w1.z; acc[7] += xv * w1.w;
    }
    u16t* Hp = H + (size_t)(rowbase + r) * 128 + c0;
    ushort4 oa = {f2b(acc[0]), f2b(acc[1]), f2b(acc[2]), f2b(acc[3])};
    ushort4 ob = {f2b(acc[4]), f2b(acc[5]), f2b(acc[6]), f2b(acc[7])};
    *(ushort4*)(Hp) = oa;
    *(ushort4*)(Hp + 4) = ob;
}

// ---------------------------------------------------------------------------
// k_count: degree histogram (1 int atomic per edge).
// ---------------------------------------------------------------------------
__global__ void k_count(const int* __restrict__ el, const int* __restrict__ flag,
                        int* __restrict__ count) {
    int wf = flag[0];
    int e = blockIdx.x * 256 + threadIdx.x;
    int hi = wf ? el[2 * (long long)e] : el[e];
    atomicAdd(&count[hi], 1);
}

// ---------------------------------------------------------------------------
// hierarchical exclusive scan: s1 block sums -> s2 scan of block sums ->
// s3 per-block scan + offset, writes row_start & cursor.
// ---------------------------------------------------------------------------
#define SCAN_BLOCKS 196  // 196*256 = 50176 >= 50000

__global__ void k_scan1(const int* __restrict__ count, int* __restrict__ bsum) {
    __shared__ int red[256];
    int b = blockIdx.x, t = threadIdx.x;
    int idx = b * 256 + t;
    red[t] = (idx < NNODE) ? count[idx] : 0;
    __syncthreads();
    for (int off = 128; off > 0; off >>= 1) {
        if (t < off) red[t] += red[t + off];
        __syncthreads();
    }
    if (t == 0) bsum[b] = red[0];
}

__global__ void k_scan2(int* __restrict__ bsum, int* __restrict__ row_start) {
    __shared__ int s[256];
    int t = threadIdx.x;
    int v = (t < SCAN_BLOCKS) ? bsum[t] : 0;
    s[t] = v;
    __syncthreads();
    for (int off = 1; off < 256; off <<= 1) {
        int u = (t >= off) ? s[t - off] : 0;
        __syncthreads();
        s[t] += u;
        __syncthreads();
    }
    if (t < SCAN_BLOCKS) bsum[t] = s[t] - v;  // exclusive block offset
    if (t == 255) row_start[NNODE] = s[255];
}

__global__ void k_scan3(const int* __restrict__ count, const int* __restrict__ bsum,
                        int* __restrict__ row_start, int* __restrict__ cursor) {
    __shared__ int s[256];
    int b = blockIdx.x, t = threadIdx.x;
    int idx = b * 256 + t;
    int v = (idx < NNODE) ? count[idx] : 0;
    s[t] = v;
    __syncthreads();
    for (int off = 1; off < 256; off <<= 1) {
        int u = (t >= off) ? s[t - off] : 0;
        __syncthreads();
        s[t] += u;
        __syncthreads();
    }
    int excl = s[t] - v + bsum[b];
    if (idx < NNODE) {
        row_start[idx] = excl;
        cursor[idx] = excl;
    }
}

// ---------------------------------------------------------------------------
// k_scatter: CSR fill — one packed u32 (ty<<16 | ti) per slot.
// ---------------------------------------------------------------------------
__global__ void k_scatter(const int* __restrict__ el, const int* __restrict__ ety,
                          const int* __restrict__ flag, int* __restrict__ cursor,
                          unsigned int* __restrict__ cpack) {
    int wf = flag[0], wt = flag[1];
    int e = blockIdx.x * 256 + threadIdx.x;
    int hi = wf ? el[2 * (long long)e]           : el[e];
    int ti = wf ? el[2 * ((long long)NEDGE + e)] : el[NEDGE + e];
    int ty = wt ? ety[2 * (long long)e]          : ety[e];
    int pos = atomicAdd(&cursor[hi], 1);
    cpack[pos] = (unsigned)ti | ((unsigned)ty << 16);
}

// ---------------------------------------------------------------------------
// k_agg: wave per head node; recompute ex per CSR edge; denominator inline
// (no atomics); gather htail bf16; out = elu(acc/den), f32 pair store.
// ---------------------------------------------------------------------------
__global__ void k_agg(const int* __restrict__ rs, const unsigned int* __restrict__ cpack,
                      const float* __restrict__ hl, const float* __restrict__ hr,
                      const float* __restrict__ heg, const u16t* __restrict__ ht,
                      float* __restrict__ den, float2* __restrict__ out) {
    __shared__ float hes[NET * NH];
    int tid = threadIdx.x;
    if (tid < NET * NH) hes[tid] = heg[tid];
    __syncthreads();
    int wave = tid >> 6, lane = tid & 63;
    int node = blockIdx.x * 4 + wave;
    int start = rs[node], end = rs[node + 1];
    int h = lane >> 4;
    float hlv = hl[node * 4 + h];
    float a0 = 0.f, a1 = 0.f, s = 0.f;
    for (int j = start; j < end; j++) {
        unsigned int cp = cpack[j];
        int ti = cp & 0xffff;
        int ty = cp >> 16;
        float att = hlv + hr[ti * 4 + h] + hes[ty * 4 + h];
        att = att > 0.f ? att : 0.2f * att;
        float exv = __expf(att);
        unsigned int hv = *(const unsigned int*)(ht + (size_t)ti * 128 + lane * 2);
        a0 += exv * b2f((u16t)(hv & 0xffff));
        a1 += exv * b2f((u16t)(hv >> 16));
        s  += exv;
    }
    if ((lane & 15) == 0) den[node * 4 + h] = s;
    float o0 = 0.f, o1 = 0.f;
    if (s > 0.f) { o0 = a0 / s; o1 = a1 / s; }
    o0 = o0 > 0.f ? o0 : expm1f(o0);
    o1 = o1 > 0.f ? o1 : expm1f(o1);
    float2 ov = {o0, o1};
    out[(size_t)node * 64 + lane] = ov;
}

// ---------------------------------------------------------------------------
// k_alpha: recompute ex per edge, alpha = ex/den[hi], f32 store (overwrites
// the htail/cpack scratch region — runs after k_agg).
// ---------------------------------------------------------------------------
__global__ void k_alpha(const int* __restrict__ el, const int* __restrict__ ety,
                        const int* __restrict__ flag,
                        const float* __restrict__ hl, const float* __restrict__ hr,
                        const float* __restrict__ heg, const float* __restrict__ den,
                        float* __restrict__ alpha) {
    __shared__ float hes[NET * NH];
    int tid = threadIdx.x;
    if (tid < NET * NH) hes[tid] = heg[tid];
    __syncthreads();
    int wf = flag[0], wt = flag[1];
    int e = blockIdx.x * 256 + tid;
    int hi = wf ? el[2 * (long long)e]           : el[e];
    int ti = wf ? el[2 * ((long long)NEDGE + e)] : el[NEDGE + e];
    int ty = wt ? ety[2 * (long long)e]          : ety[e];
    float4 l = ((const float4*)hl)[hi];
    float4 r = ((const float4*)hr)[ti];
    float4 d = ((const float4*)den)[hi];
    float v0 = l.x + r.x + hes[ty * 4 + 0];
    float v1 = l.y + r.y + hes[ty * 4 + 1];
    float v2 = l.z + r.z + hes[ty * 4 + 2];
    float v3 = l.w + r.w + hes[ty * 4 + 3];
    v0 = v0 > 0.f ? v0 : 0.2f * v0;
    v1 = v1 > 0.f ? v1 : 0.2f * v1;
    v2 = v2 > 0.f ? v2 : 0.2f * v2;
    v3 = v3 > 0.f ? v3 : 0.2f * v3;
    float4 o;
    o.x = d.x > 0.f ? __expf(v0) / d.x : 0.f;
    o.y = d.y > 0.f ? __expf(v1) / d.y : 0.f;
    o.z = d.z > 0.f ? __expf(v2) / d.z : 0.f;
    o.w = d.w > 0.f ? __expf(v3) / d.w : 0.f;
    ((float4*)alpha)[e] = o;
}

// ---------------------------------------------------------------------------
extern "C" void kernel_launch(void* const* d_in, const int* in_sizes, int n_in,
                              void* d_out, int out_size, void* d_ws, size_t ws_size,
                              hipStream_t stream) {
    const float* head = (const float*)d_in[0];
    const float* tail = (const float*)d_in[1];
    const float* W    = (const float*)d_in[2];
    const float* We   = (const float*)d_in[3];
    const float* emb  = (const float*)d_in[4];
    const float* al   = (const float*)d_in[5];
    const float* ar   = (const float*)d_in[6];
    const float* ae   = (const float*)d_in[7];
    const int*   el   = (const int*)d_in[8];
    const int*   ety  = (const int*)d_in[9];

    float* ws = (float*)d_ws;
    // ws layout: 752,356 f32 = 2.87 MiB total
    float* hl       = ws;                       // 200,000
    float* hr       = ws + 200000;              // 200,000
    float* wl       = ws + 400000;              // 1,024
    float* wr       = ws + 401024;              // 1,024
    float* heg      = ws + 402048;              // 32
    int*   flag     = (int*)(ws + 402080);      // 16
    int*   bsum     = (int*)(ws + 402096);      // 256
    float* den      = ws + 402352;              // 200,000
    int*   count    = (int*)(ws + 602352);      // 50,000
    int*   cursor   = (int*)(ws + 652352);      // 50,000
    int*   row_start= (int*)(ws + 702352);      // 50,001 (+3 pad)

    // d_out: f32 out [50000,128] then f32 alpha [E,4]
    float* outp   = (float*)d_out;              // 6,400,000 f32
    float* alphap = (float*)d_out + 6400000;    // 6,400,000 f32
    // scratch parked inside the alpha region until k_alpha overwrites it:
    //   htail bf16 [50000*128] = first 3.2M f32-slots
    //   cpack u32 [NEDGE]      = next 1.6M f32-slots
    u16t*        htail = (u16t*)alphap;
    unsigned int* cpack = (unsigned int*)(alphap + 3200000);

    (void)hipMemsetAsync(count, 0, NNODE * sizeof(int), stream);

    k_detect<<<1, 128, 0, stream>>>(el, ety, flag);
    k_prep<<<1, 256, 0, stream>>>(W, We, emb, al, ar, ae, wl, wr, heg);
    k_rowdot<<<NNODE / 4, 256, 0, stream>>>(head, wl, hl);
    k_rowdot<<<NNODE / 4, 256, 0, stream>>>(tail, wr, hr);
    k_gemm<<<NNODE / 16, 256, 0, stream>>>(tail, W, htail);
    k_count<<<NEDGE / 256, 256, 0, stream>>>(el, flag, count);
    k_scan1<<<SCAN_BLOCKS, 256, 0, stream>>>(count, bsum);
    k_scan2<<<1, 256, 0, stream>>>(bsum, row_start);
    k_scan3<<<SCAN_BLOCKS, 256, 0, stream>>>(count, bsum, row_start, cursor);
    k_scatter<<<NEDGE / 256, 256, 0, stream>>>(el, ety, flag, cursor, cpack);
    k_agg<<<NNODE / 4, 256, 0, stream>>>(row_start, cpack, hl, hr, heg, htail,
                                         den, (float2*)outp);
    k_alpha<<<NEDGE / 256, 256, 0, stream>>>(el, ety, flag, hl, hr, heg, den, alphap);
}

// Round 8
// 582.672 us; speedup vs baseline: 2.0633x; 1.3296x over previous
//
#include <hip/hip_runtime.h>
#include <hip/hip_bf16.h>
#include <string.h>

#define NNODE 50000
#define NEDGE 1600000
#define INF   256
#define OUTF  32
#define NH    4
#define EF    64
#define NET   5

typedef unsigned short u16t;
typedef __attribute__((ext_vector_type(8))) short short8;
typedef __attribute__((ext_vector_type(4))) float f32x4;

__device__ __forceinline__ float b2f(u16t u) {
    union { unsigned int i; float f; } v; v.i = ((unsigned int)u) << 16; return v.f;
}
__device__ __forceinline__ u16t f2b(float f) {
    __hip_bfloat16 h = __float2bfloat16(f);
    u16t u; memcpy(&u, &h, 2); return u;
}

// ---------------------------------------------------------------------------
// k_detect: int64-vs-int32 layout sniff (odd words all zero => int64).
// ---------------------------------------------------------------------------
__global__ void k_detect(const int* __restrict__ el, const int* __restrict__ ety,
                         int* __restrict__ flag) {
    int tid = threadIdx.x;
    int w = tid >> 6, lane = tid & 63;
    const int* p = (w == 0) ? el : ety;
    int x = p[2 * lane + 1];
    unsigned long long b = __ballot(x != 0);
    if (lane == 0) flag[w] = (b == 0ULL) ? 1 : 0;
}

// ---------------------------------------------------------------------------
// k_prep: fold a_l/a_r into W -> wl/wr [256][4]; h_e [5][4] from folded W_e.
// ---------------------------------------------------------------------------
__global__ void k_prep(const float* __restrict__ W, const float* __restrict__ We,
                       const float* __restrict__ emb, const float* __restrict__ al,
                       const float* __restrict__ ar, const float* __restrict__ ae,
                       float* __restrict__ wl, float* __restrict__ wr,
                       float* __restrict__ he) {
    __shared__ float wes[EF * NH];
    int tid = threadIdx.x;
    {
        int k = tid;  // 0..255
        for (int h = 0; h < NH; h++) {
            float accl = 0.f, accr = 0.f;
            for (int d = 0; d < OUTF; d++) {
                float w = W[k * (NH * OUTF) + h * OUTF + d];
                accl += w * al[h * OUTF + d];
                accr += w * ar[h * OUTF + d];
            }
            wl[k * NH + h] = accl;
            wr[k * NH + h] = accr;
        }
    }
    if (tid < EF) {
        int k = tid;
        for (int h = 0; h < NH; h++) {
            float s = 0.f;
            for (int d = 0; d < EF; d++)
                s += We[k * (NH * EF) + h * EF + d] * ae[h * EF + d];
            wes[k * NH + h] = s;
        }
    }
    __syncthreads();
    if (tid < NET * NH) {
        int t = tid / NH, h = tid % NH;
        float s = 0.f;
        for (int k = 0; k < EF; k++)
            s += emb[t * EF + k] * wes[k * NH + h];
        he[tid] = s;
    }
}

// ---------------------------------------------------------------------------
// k_prepw: repack W [256][128] fp32 -> bf16 B-fragments in the exact order
// MFMA lanes read them: Wfrag[((tile*8+ks)*64+lane)*8 + j] = W[k][n]
// with n = tile*16 + (lane&15), k = ks*32 + (lane>>4)*8 + j.
// ---------------------------------------------------------------------------
__global__ void k_prepw(const float* __restrict__ W, u16t* __restrict__ Wfrag) {
    int idx = blockIdx.x * 256 + threadIdx.x;  // 0..32767
    int j    = idx & 7;
    int lane = (idx >> 3) & 63;
    int ks   = (idx >> 9) & 7;
    int tile = idx >> 12;
    int n = tile * 16 + (lane & 15);
    int k = ks * 32 + (lane >> 4) * 8 + j;
    Wfrag[idx] = f2b(W[k * 128 + n]);
}

// ---------------------------------------------------------------------------
// k_rowdot: out[row][0..3] = X[row,:] @ wvec; one wave per row.
// ---------------------------------------------------------------------------
__global__ void k_rowdot(const float* __restrict__ X, const float* __restrict__ wvec,
                         float* __restrict__ out) {
    __shared__ float w[INF * NH];
    int tid = threadIdx.x;
    ((float4*)w)[tid] = ((const float4*)wvec)[tid];
    __syncthreads();
    int wave = tid >> 6, lane = tid & 63;
    int row = blockIdx.x * 4 + wave;
    float4 xv = *(const float4*)(X + (size_t)row * INF + lane * 4);
    float xs[4] = {xv.x, xv.y, xv.z, xv.w};
    float4 acc = {0.f, 0.f, 0.f, 0.f};
#pragma unroll
    for (int j = 0; j < 4; j++) {
        float xf = xs[j];
        float4 wv = ((float4*)w)[lane * 4 + j];
        acc.x += xf * wv.x; acc.y += xf * wv.y;
        acc.z += xf * wv.z; acc.w += xf * wv.w;
    }
#pragma unroll
    for (int off = 32; off > 0; off >>= 1) {
        acc.x += __shfl_xor(acc.x, off);
        acc.y += __shfl_xor(acc.y, off);
        acc.z += __shfl_xor(acc.z, off);
        acc.w += __shfl_xor(acc.w, off);
    }
    if (lane == 0) ((float4*)out)[row] = acc;
}

// ---------------------------------------------------------------------------
// k_gemm: htail = tail @ W via MFMA bf16. Block = 16 rows, 4 waves;
// each wave owns two 16-col tiles; 8 K-steps of 32.
// A: LDS bf16 [16][264] (pad breaks bank alignment), A[m=lane&15][k=quad*8+j].
// B: Wfrag coalesced frag-order loads. D: col=lane&15, row=quad*4+reg.
// ---------------------------------------------------------------------------
__global__ void k_gemm(const float* __restrict__ X, const u16t* __restrict__ Wfrag,
                       u16t* __restrict__ H) {
    __shared__ __attribute__((aligned(16))) u16t alds[16 * 264];
    int tid = threadIdx.x;
    int rowbase = blockIdx.x * 16;
    for (int i = tid; i < 1024; i += 256) {
        int row = i >> 6;
        int kc = (i & 63) * 4;
        float4 v = *(const float4*)(X + (size_t)(rowbase + row) * INF + kc);
        u16t* d = alds + row * 264 + kc;
        d[0] = f2b(v.x); d[1] = f2b(v.y); d[2] = f2b(v.z); d[3] = f2b(v.w);
    }
    __syncthreads();
    int wave = tid >> 6, lane = tid & 63;
    int m = lane & 15, quad = lane >> 4;
    int t0 = wave * 2, t1 = t0 + 1;
    f32x4 acc0 = {0.f, 0.f, 0.f, 0.f};
    f32x4 acc1 = {0.f, 0.f, 0.f, 0.f};
#pragma unroll
    for (int ks = 0; ks < 8; ks++) {
        short8 a  = *(const short8*)(alds + m * 264 + ks * 32 + quad * 8);
        short8 b0 = *(const short8*)(Wfrag + (((t0 * 8 + ks) * 64 + lane) << 3));
        short8 b1 = *(const short8*)(Wfrag + (((t1 * 8 + ks) * 64 + lane) << 3));
        acc0 = __builtin_amdgcn_mfma_f32_16x16x32_bf16(a, b0, acc0, 0, 0, 0);
        acc1 = __builtin_amdgcn_mfma_f32_16x16x32_bf16(a, b1, acc1, 0, 0, 0);
    }
    u16t* Hp = H + (size_t)rowbase * 128;
#pragma unroll
    for (int r = 0; r < 4; r++) {
        int row = quad * 4 + r;
        Hp[(size_t)row * 128 + t0 * 16 + m] = f2b(acc0[r]);
        Hp[(size_t)row * 128 + t1 * 16 + m] = f2b(acc1[r]);
    }
}

// ---------------------------------------------------------------------------
// k_count: degree histogram (1 int atomic per edge).
// ---------------------------------------------------------------------------
__global__ void k_count(const int* __restrict__ el, const int* __restrict__ flag,
                        int* __restrict__ count) {
    int wf = flag[0];
    int e = blockIdx.x * 256 + threadIdx.x;
    int hi = wf ? el[2 * (long long)e] : el[e];
    atomicAdd(&count[hi], 1);
}

// ---------------------------------------------------------------------------
// hierarchical exclusive scan.
// ---------------------------------------------------------------------------
#define SCAN_BLOCKS 196  // 196*256 = 50176 >= 50000

__global__ void k_scan1(const int* __restrict__ count, int* __restrict__ bsum) {
    __shared__ int red[256];
    int b = blockIdx.x, t = threadIdx.x;
    int idx = b * 256 + t;
    red[t] = (idx < NNODE) ? count[idx] : 0;
    __syncthreads();
    for (int off = 128; off > 0; off >>= 1) {
        if (t < off) red[t] += red[t + off];
        __syncthreads();
    }
    if (t == 0) bsum[b] = red[0];
}

__global__ void k_scan2(int* __restrict__ bsum, int* __restrict__ row_start) {
    __shared__ int s[256];
    int t = threadIdx.x;
    int v = (t < SCAN_BLOCKS) ? bsum[t] : 0;
    s[t] = v;
    __syncthreads();
    for (int off = 1; off < 256; off <<= 1) {
        int u = (t >= off) ? s[t - off] : 0;
        __syncthreads();
        s[t] += u;
        __syncthreads();
    }
    if (t < SCAN_BLOCKS) bsum[t] = s[t] - v;  // exclusive block offset
    if (t == 255) row_start[NNODE] = s[255];
}

__global__ void k_scan3(const int* __restrict__ count, const int* __restrict__ bsum,
                        int* __restrict__ row_start, int* __restrict__ cursor) {
    __shared__ int s[256];
    int b = blockIdx.x, t = threadIdx.x;
    int idx = b * 256 + t;
    int v = (idx < NNODE) ? count[idx] : 0;
    s[t] = v;
    __syncthreads();
    for (int off = 1; off < 256; off <<= 1) {
        int u = (t >= off) ? s[t - off] : 0;
        __syncthreads();
        s[t] += u;
        __syncthreads();
    }
    int excl = s[t] - v + bsum[b];
    if (idx < NNODE) {
        row_start[idx] = excl;
        cursor[idx] = excl;
    }
}

// ---------------------------------------------------------------------------
// k_scatter: CSR fill — one packed u32 (ty<<16 | ti) per slot.
// ---------------------------------------------------------------------------
__global__ void k_scatter(const int* __restrict__ el, const int* __restrict__ ety,
                          const int* __restrict__ flag, int* __restrict__ cursor,
                          unsigned int* __restrict__ cpack) {
    int wf = flag[0], wt = flag[1];
    int e = blockIdx.x * 256 + threadIdx.x;
    int hi = wf ? el[2 * (long long)e]           : el[e];
    int ti = wf ? el[2 * ((long long)NEDGE + e)] : el[NEDGE + e];
    int ty = wt ? ety[2 * (long long)e]          : ety[e];
    int pos = atomicAdd(&cursor[hi], 1);
    cpack[pos] = (unsigned)ti | ((unsigned)ty << 16);
}

// ---------------------------------------------------------------------------
// k_agg: wave per head node; recompute ex per CSR edge; denominator inline
// (no atomics); gather htail bf16; out = elu(acc/den), f32 pair store.
// ---------------------------------------------------------------------------
__global__ void k_agg(const int* __restrict__ rs, const unsigned int* __restrict__ cpack,
                      const float* __restrict__ hl, const float* __restrict__ hr,
                      const float* __restrict__ heg, const u16t* __restrict__ ht,
                      float* __restrict__ den, float2* __restrict__ out) {
    __shared__ float hes[NET * NH];
    int tid = threadIdx.x;
    if (tid < NET * NH) hes[tid] = heg[tid];
    __syncthreads();
    int wave = tid >> 6, lane = tid & 63;
    int node = blockIdx.x * 4 + wave;
    int start = rs[node], end = rs[node + 1];
    int h = lane >> 4;
    float hlv = hl[node * 4 + h];
    float a0 = 0.f, a1 = 0.f, s = 0.f;
    for (int j = start; j < end; j++) {
        unsigned int cp = cpack[j];
        int ti = cp & 0xffff;
        int ty = cp >> 16;
        float att = hlv + hr[ti * 4 + h] + hes[ty * 4 + h];
        att = att > 0.f ? att : 0.2f * att;
        float exv = __expf(att);
        unsigned int hv = *(const unsigned int*)(ht + (size_t)ti * 128 + lane * 2);
        a0 += exv * b2f((u16t)(hv & 0xffff));
        a1 += exv * b2f((u16t)(hv >> 16));
        s  += exv;
    }
    if ((lane & 15) == 0) den[node * 4 + h] = s;
    float o0 = 0.f, o1 = 0.f;
    if (s > 0.f) { o0 = a0 / s; o1 = a1 / s; }
    o0 = o0 > 0.f ? o0 : expm1f(o0);
    o1 = o1 > 0.f ? o1 : expm1f(o1);
    float2 ov = {o0, o1};
    out[(size_t)node * 64 + lane] = ov;
}

// ---------------------------------------------------------------------------
// k_alpha: recompute ex per edge, alpha = ex/den[hi], f32 store (overwrites
// the htail/cpack scratch region — runs after k_agg).
// ---------------------------------------------------------------------------
__global__ void k_alpha(const int* __restrict__ el, const int* __restrict__ ety,
                        const int* __restrict__ flag,
                        const float* __restrict__ hl, const float* __restrict__ hr,
                        const float* __restrict__ heg, const float* __restrict__ den,
                        float* __restrict__ alpha) {
    __shared__ float hes[NET * NH];
    int tid = threadIdx.x;
    if (tid < NET * NH) hes[tid] = heg[tid];
    __syncthreads();
    int wf = flag[0], wt = flag[1];
    int e = blockIdx.x * 256 + tid;
    int hi = wf ? el[2 * (long long)e]           : el[e];
    int ti = wf ? el[2 * ((long long)NEDGE + e)] : el[NEDGE + e];
    int ty = wt ? ety[2 * (long long)e]          : ety[e];
    float4 l = ((const float4*)hl)[hi];
    float4 r = ((const float4*)hr)[ti];
    float4 d = ((const float4*)den)[hi];
    float v0 = l.x + r.x + hes[ty * 4 + 0];
    float v1 = l.y + r.y + hes[ty * 4 + 1];
    float v2 = l.z + r.z + hes[ty * 4 + 2];
    float v3 = l.w + r.w + hes[ty * 4 + 3];
    v0 = v0 > 0.f ? v0 : 0.2f * v0;
    v1 = v1 > 0.f ? v1 : 0.2f * v1;
    v2 = v2 > 0.f ? v2 : 0.2f * v2;
    v3 = v3 > 0.f ? v3 : 0.2f * v3;
    float4 o;
    o.x = d.x > 0.f ? __expf(v0) / d.x : 0.f;
    o.y = d.y > 0.f ? __expf(v1) / d.y : 0.f;
    o.z = d.z > 0.f ? __expf(v2) / d.z : 0.f;
    o.w = d.w > 0.f ? __expf(v3) / d.w : 0.f;
    ((float4*)alpha)[e] = o;
}

// ---------------------------------------------------------------------------
extern "C" void kernel_launch(void* const* d_in, const int* in_sizes, int n_in,
                              void* d_out, int out_size, void* d_ws, size_t ws_size,
                              hipStream_t stream) {
    const float* head = (const float*)d_in[0];
    const float* tail = (const float*)d_in[1];
    const float* W    = (const float*)d_in[2];
    const float* We   = (const float*)d_in[3];
    const float* emb  = (const float*)d_in[4];
    const float* al   = (const float*)d_in[5];
    const float* ar   = (const float*)d_in[6];
    const float* ae   = (const float*)d_in[7];
    const int*   el   = (const int*)d_in[8];
    const int*   ety  = (const int*)d_in[9];

    float* ws = (float*)d_ws;
    // ws layout (f32-slot offsets), ~2.94 MiB total
    float* hl       = ws;                       // 200,000
    float* hr       = ws + 200000;              // 200,000
    float* wl       = ws + 400000;              // 1,024
    float* wr       = ws + 401024;              // 1,024
    float* heg      = ws + 402048;              // 32
    int*   flag     = (int*)(ws + 402080);      // 16
    int*   bsum     = (int*)(ws + 402096);      // 256
    float* den      = ws + 402352;              // 200,000
    int*   count    = (int*)(ws + 602352);      // 50,000
    int*   cursor   = (int*)(ws + 652352);      // 50,000
    int*   row_start= (int*)(ws + 702352);      // 50,001 (+3 pad)
    u16t*  Wfrag    = (u16t*)(ws + 752356);     // 32,768 bf16 (16,384 f32)

    // d_out: f32 out [50000,128] then f32 alpha [E,4]
    float* outp   = (float*)d_out;              // 6,400,000 f32
    float* alphap = (float*)d_out + 6400000;    // 6,400,000 f32
    // scratch parked inside the alpha region until k_alpha overwrites it:
    u16t*         htail = (u16t*)alphap;                       // 6.4M bf16
    unsigned int* cpack = (unsigned int*)(alphap + 3200000);   // 1.6M u32

    (void)hipMemsetAsync(count, 0, NNODE * sizeof(int), stream);

    k_detect<<<1, 128, 0, stream>>>(el, ety, flag);
    k_prep<<<1, 256, 0, stream>>>(W, We, emb, al, ar, ae, wl, wr, heg);
    k_prepw<<<128, 256, 0, stream>>>(W, Wfrag);
    k_rowdot<<<NNODE / 4, 256, 0, stream>>>(head, wl, hl);
    k_rowdot<<<NNODE / 4, 256, 0, stream>>>(tail, wr, hr);
    k_gemm<<<NNODE / 16, 256, 0, stream>>>(tail, Wfrag, htail);
    k_count<<<NEDGE / 256, 256, 0, stream>>>(el, flag, count);
    k_scan1<<<SCAN_BLOCKS, 256, 0, stream>>>(count, bsum);
    k_scan2<<<1, 256, 0, stream>>>(bsum, row_start);
    k_scan3<<<SCAN_BLOCKS, 256, 0, stream>>>(count, bsum, row_start, cursor);
    k_scatter<<<NEDGE / 256, 256, 0, stream>>>(el, ety, flag, cursor, cpack);
    k_agg<<<NNODE / 4, 256, 0, stream>>>(row_start, cpack, hl, hr, heg, htail,
                                         den, (float2*)outp);
    k_alpha<<<NEDGE / 256, 256, 0, stream>>>(el, ety, flag, hl, hr, heg, den, alphap);
}

// Round 9
// 505.121 us; speedup vs baseline: 2.3800x; 1.1535x over previous
//
#include <hip/hip_runtime.h>
#include <hip/hip_bf16.h>
#include <string.h>

#define NNODE 50000
#define NEDGE 1600000
#define INF   256
#define OUTF  32
#define NH    4
#define EF    64
#define NET   5

typedef unsigned short u16t;
typedef __attribute__((ext_vector_type(8))) short short8;
typedef __attribute__((ext_vector_type(4))) float f32x4;

__device__ __forceinline__ float b2f(u16t u) {
    union { unsigned int i; float f; } v; v.i = ((unsigned int)u) << 16; return v.f;
}
__device__ __forceinline__ u16t f2b(float f) {
    __hip_bfloat16 h = __float2bfloat16(f);
    u16t u; memcpy(&u, &h, 2); return u;
}

// ---------------------------------------------------------------------------
// k_detect: int64-vs-int32 layout sniff (odd words all zero => int64).
// ---------------------------------------------------------------------------
__global__ void k_detect(const int* __restrict__ el, const int* __restrict__ ety,
                         int* __restrict__ flag) {
    int tid = threadIdx.x;
    int w = tid >> 6, lane = tid & 63;
    const int* p = (w == 0) ? el : ety;
    int x = p[2 * lane + 1];
    unsigned long long b = __ballot(x != 0);
    if (lane == 0) flag[w] = (b == 0ULL) ? 1 : 0;
}

// ---------------------------------------------------------------------------
// k_prep: fold a_l/a_r into W -> wl/wr [256][4]; h_e [5][4] from folded W_e.
// ---------------------------------------------------------------------------
__global__ void k_prep(const float* __restrict__ W, const float* __restrict__ We,
                       const float* __restrict__ emb, const float* __restrict__ al,
                       const float* __restrict__ ar, const float* __restrict__ ae,
                       float* __restrict__ wl, float* __restrict__ wr,
                       float* __restrict__ he) {
    __shared__ float wes[EF * NH];
    int tid = threadIdx.x;
    {
        int k = tid;  // 0..255
        for (int h = 0; h < NH; h++) {
            float accl = 0.f, accr = 0.f;
            for (int d = 0; d < OUTF; d++) {
                float w = W[k * (NH * OUTF) + h * OUTF + d];
                accl += w * al[h * OUTF + d];
                accr += w * ar[h * OUTF + d];
            }
            wl[k * NH + h] = accl;
            wr[k * NH + h] = accr;
        }
    }
    if (tid < EF) {
        int k = tid;
        for (int h = 0; h < NH; h++) {
            float s = 0.f;
            for (int d = 0; d < EF; d++)
                s += We[k * (NH * EF) + h * EF + d] * ae[h * EF + d];
            wes[k * NH + h] = s;
        }
    }
    __syncthreads();
    if (tid < NET * NH) {
        int t = tid / NH, h = tid % NH;
        float s = 0.f;
        for (int k = 0; k < EF; k++)
            s += emb[t * EF + k] * wes[k * NH + h];
        he[tid] = s;
    }
}

// ---------------------------------------------------------------------------
// k_prepw: repack W [256][128] fp32 -> bf16 B-fragments in MFMA lane order.
// ---------------------------------------------------------------------------
__global__ void k_prepw(const float* __restrict__ W, u16t* __restrict__ Wfrag) {
    int idx = blockIdx.x * 256 + threadIdx.x;  // 0..32767
    int j    = idx & 7;
    int lane = (idx >> 3) & 63;
    int ks   = (idx >> 9) & 7;
    int tile = idx >> 12;
    int n = tile * 16 + (lane & 15);
    int k = ks * 32 + (lane >> 4) * 8 + j;
    Wfrag[idx] = f2b(W[k * 128 + n]);
}

// ---------------------------------------------------------------------------
// k_fuseA: blocks [0,12500) rowdot(head->hl), [12500,25000) rowdot(tail->hr),
// [25000,31250) degree count. Overlaps VALU/HBM waves with atomic waves.
// ---------------------------------------------------------------------------
__global__ void k_fuseA(const float* __restrict__ head, const float* __restrict__ tail,
                        const float* __restrict__ wl, const float* __restrict__ wr,
                        const int* __restrict__ el, const int* __restrict__ flag,
                        int* __restrict__ count, float* __restrict__ hl,
                        float* __restrict__ hr) {
    __shared__ float w[INF * NH];
    int b = blockIdx.x;
    int tid = threadIdx.x;
    if (b < 25000) {
        int ishead = (b < 12500);
        const float* X  = ishead ? head : tail;
        const float* wv = ishead ? wl : wr;
        float* o        = ishead ? hl : hr;
        int bb          = ishead ? b : b - 12500;
        ((float4*)w)[tid] = ((const float4*)wv)[tid];
        __syncthreads();
        int wave = tid >> 6, lane = tid & 63;
        int row = bb * 4 + wave;
        float4 xv = *(const float4*)(X + (size_t)row * INF + lane * 4);
        float xs[4] = {xv.x, xv.y, xv.z, xv.w};
        float4 acc = {0.f, 0.f, 0.f, 0.f};
#pragma unroll
        for (int j = 0; j < 4; j++) {
            float xf = xs[j];
            float4 wvv = ((float4*)w)[lane * 4 + j];
            acc.x += xf * wvv.x; acc.y += xf * wvv.y;
            acc.z += xf * wvv.z; acc.w += xf * wvv.w;
        }
#pragma unroll
        for (int off = 32; off > 0; off >>= 1) {
            acc.x += __shfl_xor(acc.x, off);
            acc.y += __shfl_xor(acc.y, off);
            acc.z += __shfl_xor(acc.z, off);
            acc.w += __shfl_xor(acc.w, off);
        }
        if (lane == 0) ((float4*)o)[row] = acc;
    } else {
        int e = (b - 25000) * 256 + tid;
        int wf = flag[0];
        int hi = wf ? el[2 * (long long)e] : el[e];
        atomicAdd(&count[hi], 1);
    }
}

// ---------------------------------------------------------------------------
// hierarchical exclusive scan.
// ---------------------------------------------------------------------------
#define SCAN_BLOCKS 196  // 196*256 = 50176 >= 50000

__global__ void k_scan1(const int* __restrict__ count, int* __restrict__ bsum) {
    __shared__ int red[256];
    int b = blockIdx.x, t = threadIdx.x;
    int idx = b * 256 + t;
    red[t] = (idx < NNODE) ? count[idx] : 0;
    __syncthreads();
    for (int off = 128; off > 0; off >>= 1) {
        if (t < off) red[t] += red[t + off];
        __syncthreads();
    }
    if (t == 0) bsum[b] = red[0];
}

__global__ void k_scan2(int* __restrict__ bsum, int* __restrict__ row_start) {
    __shared__ int s[256];
    int t = threadIdx.x;
    int v = (t < SCAN_BLOCKS) ? bsum[t] : 0;
    s[t] = v;
    __syncthreads();
    for (int off = 1; off < 256; off <<= 1) {
        int u = (t >= off) ? s[t - off] : 0;
        __syncthreads();
        s[t] += u;
        __syncthreads();
    }
    if (t < SCAN_BLOCKS) bsum[t] = s[t] - v;  // exclusive block offset
    if (t == 255) row_start[NNODE] = s[255];
}

__global__ void k_scan3(const int* __restrict__ count, const int* __restrict__ bsum,
                        int* __restrict__ row_start, int* __restrict__ cursor) {
    __shared__ int s[256];
    int b = blockIdx.x, t = threadIdx.x;
    int idx = b * 256 + t;
    int v = (idx < NNODE) ? count[idx] : 0;
    s[t] = v;
    __syncthreads();
    for (int off = 1; off < 256; off <<= 1) {
        int u = (t >= off) ? s[t - off] : 0;
        __syncthreads();
        s[t] += u;
        __syncthreads();
    }
    int excl = s[t] - v + bsum[b];
    if (idx < NNODE) {
        row_start[idx] = excl;
        cursor[idx] = excl;
    }
}

// ---------------------------------------------------------------------------
// k_fuseB: blocks [0,3125) MFMA gemm (tail @ W -> htail bf16),
// [3125,9375) CSR scatter. MFMA waves overlap atomic waves.
// ---------------------------------------------------------------------------
__global__ void k_fuseB(const float* __restrict__ X, const u16t* __restrict__ Wfrag,
                        u16t* __restrict__ H, const int* __restrict__ el,
                        const int* __restrict__ ety, const int* __restrict__ flag,
                        int* __restrict__ cursor, unsigned int* __restrict__ cpack) {
    __shared__ __attribute__((aligned(16))) u16t alds[16 * 264];
    int b = blockIdx.x;
    int tid = threadIdx.x;
    if (b < 3125) {
        int rowbase = b * 16;
        for (int i = tid; i < 1024; i += 256) {
            int row = i >> 6;
            int kc = (i & 63) * 4;
            float4 v = *(const float4*)(X + (size_t)(rowbase + row) * INF + kc);
            u16t* d = alds + row * 264 + kc;
            d[0] = f2b(v.x); d[1] = f2b(v.y); d[2] = f2b(v.z); d[3] = f2b(v.w);
        }
        __syncthreads();
        int wave = tid >> 6, lane = tid & 63;
        int m = lane & 15, quad = lane >> 4;
        int t0 = wave * 2, t1 = t0 + 1;
        f32x4 acc0 = {0.f, 0.f, 0.f, 0.f};
        f32x4 acc1 = {0.f, 0.f, 0.f, 0.f};
#pragma unroll
        for (int ks = 0; ks < 8; ks++) {
            short8 a  = *(const short8*)(alds + m * 264 + ks * 32 + quad * 8);
            short8 b0 = *(const short8*)(Wfrag + (((t0 * 8 + ks) * 64 + lane) << 3));
            short8 b1 = *(const short8*)(Wfrag + (((t1 * 8 + ks) * 64 + lane) << 3));
            acc0 = __builtin_amdgcn_mfma_f32_16x16x32_bf16(a, b0, acc0, 0, 0, 0);
            acc1 = __builtin_amdgcn_mfma_f32_16x16x32_bf16(a, b1, acc1, 0, 0, 0);
        }
        u16t* Hp = H + (size_t)rowbase * 128;
#pragma unroll
        for (int r = 0; r < 4; r++) {
            int row = quad * 4 + r;
            Hp[(size_t)row * 128 + t0 * 16 + m] = f2b(acc0[r]);
            Hp[(size_t)row * 128 + t1 * 16 + m] = f2b(acc1[r]);
        }
    } else {
        int e = (b - 3125) * 256 + tid;
        int wf = flag[0], wt = flag[1];
        int hi = wf ? el[2 * (long long)e]           : el[e];
        int ti = wf ? el[2 * ((long long)NEDGE + e)] : el[NEDGE + e];
        int ty = wt ? ety[2 * (long long)e]          : ety[e];
        int pos = atomicAdd(&cursor[hi], 1);
        cpack[pos] = (unsigned)ti | ((unsigned)ty << 16);
    }
}

// ---------------------------------------------------------------------------
// k_agg: wave per head node; 4-wide batched edge loop for MLP; denominator
// inline; gather htail bf16; out = elu(acc/den), f32 pair store.
// ---------------------------------------------------------------------------
__global__ void k_agg(const int* __restrict__ rs, const unsigned int* __restrict__ cpack,
                      const float* __restrict__ hl, const float* __restrict__ hr,
                      const float* __restrict__ heg, const u16t* __restrict__ ht,
                      float* __restrict__ den, float2* __restrict__ out) {
    __shared__ float hes[NET * NH];
    int tid = threadIdx.x;
    if (tid < NET * NH) hes[tid] = heg[tid];
    __syncthreads();
    int wave = tid >> 6, lane = tid & 63;
    int node = blockIdx.x * 4 + wave;
    int start = rs[node], end = rs[node + 1];
    int h = lane >> 4;
    float hlv = hl[node * 4 + h];
    float a0 = 0.f, a1 = 0.f, s = 0.f;
    int j = start;
    for (; j + 4 <= end; j += 4) {
        unsigned c0 = cpack[j], c1 = cpack[j + 1], c2 = cpack[j + 2], c3 = cpack[j + 3];
        int t0 = c0 & 0xffff, t1 = c1 & 0xffff, t2 = c2 & 0xffff, t3 = c3 & 0xffff;
        float r0 = hr[t0 * 4 + h], r1 = hr[t1 * 4 + h];
        float r2 = hr[t2 * 4 + h], r3 = hr[t3 * 4 + h];
        unsigned v0 = *(const unsigned*)(ht + (size_t)t0 * 128 + lane * 2);
        unsigned v1 = *(const unsigned*)(ht + (size_t)t1 * 128 + lane * 2);
        unsigned v2 = *(const unsigned*)(ht + (size_t)t2 * 128 + lane * 2);
        unsigned v3 = *(const unsigned*)(ht + (size_t)t3 * 128 + lane * 2);
        float x0 = hlv + r0 + hes[(c0 >> 16) * 4 + h];
        float x1 = hlv + r1 + hes[(c1 >> 16) * 4 + h];
        float x2 = hlv + r2 + hes[(c2 >> 16) * 4 + h];
        float x3 = hlv + r3 + hes[(c3 >> 16) * 4 + h];
        x0 = x0 > 0.f ? x0 : 0.2f * x0;
        x1 = x1 > 0.f ? x1 : 0.2f * x1;
        x2 = x2 > 0.f ? x2 : 0.2f * x2;
        x3 = x3 > 0.f ? x3 : 0.2f * x3;
        float e0 = __expf(x0), e1 = __expf(x1), e2 = __expf(x2), e3 = __expf(x3);
        a0 += e0 * b2f((u16t)(v0 & 0xffff)) + e1 * b2f((u16t)(v1 & 0xffff))
            + e2 * b2f((u16t)(v2 & 0xffff)) + e3 * b2f((u16t)(v3 & 0xffff));
        a1 += e0 * b2f((u16t)(v0 >> 16)) + e1 * b2f((u16t)(v1 >> 16))
            + e2 * b2f((u16t)(v2 >> 16)) + e3 * b2f((u16t)(v3 >> 16));
        s  += e0 + e1 + e2 + e3;
    }
    for (; j < end; j++) {
        unsigned cp = cpack[j];
        int ti = cp & 0xffff;
        int ty = cp >> 16;
        float att = hlv + hr[ti * 4 + h] + hes[ty * 4 + h];
        att = att > 0.f ? att : 0.2f * att;
        float exv = __expf(att);
        unsigned int hv = *(const unsigned*)(ht + (size_t)ti * 128 + lane * 2);
        a0 += exv * b2f((u16t)(hv & 0xffff));
        a1 += exv * b2f((u16t)(hv >> 16));
        s  += exv;
    }
    if ((lane & 15) == 0) den[node * 4 + h] = s;
    float o0 = 0.f, o1 = 0.f;
    if (s > 0.f) { o0 = a0 / s; o1 = a1 / s; }
    o0 = o0 > 0.f ? o0 : expm1f(o0);
    o1 = o1 > 0.f ? o1 : expm1f(o1);
    float2 ov = {o0, o1};
    out[(size_t)node * 64 + lane] = ov;
}

// ---------------------------------------------------------------------------
// k_alpha: recompute ex per edge, alpha = ex/den[hi], f32 store (overwrites
// the htail/cpack scratch region — runs after k_agg).
// ---------------------------------------------------------------------------
__global__ void k_alpha(const int* __restrict__ el, const int* __restrict__ ety,
                        const int* __restrict__ flag,
                        const float* __restrict__ hl, const float* __restrict__ hr,
                        const float* __restrict__ heg, const float* __restrict__ den,
                        float* __restrict__ alpha) {
    __shared__ float hes[NET * NH];
    int tid = threadIdx.x;
    if (tid < NET * NH) hes[tid] = heg[tid];
    __syncthreads();
    int wf = flag[0], wt = flag[1];
    int e = blockIdx.x * 256 + tid;
    int hi = wf ? el[2 * (long long)e]           : el[e];
    int ti = wf ? el[2 * ((long long)NEDGE + e)] : el[NEDGE + e];
    int ty = wt ? ety[2 * (long long)e]          : ety[e];
    float4 l = ((const float4*)hl)[hi];
    float4 r = ((const float4*)hr)[ti];
    float4 d = ((const float4*)den)[hi];
    float v0 = l.x + r.x + hes[ty * 4 + 0];
    float v1 = l.y + r.y + hes[ty * 4 + 1];
    float v2 = l.z + r.z + hes[ty * 4 + 2];
    float v3 = l.w + r.w + hes[ty * 4 + 3];
    v0 = v0 > 0.f ? v0 : 0.2f * v0;
    v1 = v1 > 0.f ? v1 : 0.2f * v1;
    v2 = v2 > 0.f ? v2 : 0.2f * v2;
    v3 = v3 > 0.f ? v3 : 0.2f * v3;
    float4 o;
    o.x = d.x > 0.f ? __expf(v0) / d.x : 0.f;
    o.y = d.y > 0.f ? __expf(v1) / d.y : 0.f;
    o.z = d.z > 0.f ? __expf(v2) / d.z : 0.f;
    o.w = d.w > 0.f ? __expf(v3) / d.w : 0.f;
    ((float4*)alpha)[e] = o;
}

// ---------------------------------------------------------------------------
extern "C" void kernel_launch(void* const* d_in, const int* in_sizes, int n_in,
                              void* d_out, int out_size, void* d_ws, size_t ws_size,
                              hipStream_t stream) {
    const float* head = (const float*)d_in[0];
    const float* tail = (const float*)d_in[1];
    const float* W    = (const float*)d_in[2];
    const float* We   = (const float*)d_in[3];
    const float* emb  = (const float*)d_in[4];
    const float* al   = (const float*)d_in[5];
    const float* ar   = (const float*)d_in[6];
    const float* ae   = (const float*)d_in[7];
    const int*   el   = (const int*)d_in[8];
    const int*   ety  = (const int*)d_in[9];

    float* ws = (float*)d_ws;
    // ws layout (f32-slot offsets), ~3.1 MiB total
    float* hl       = ws;                       // 200,000
    float* hr       = ws + 200000;              // 200,000
    float* wl       = ws + 400000;              // 1,024
    float* wr       = ws + 401024;              // 1,024
    float* heg      = ws + 402048;              // 32
    int*   flag     = (int*)(ws + 402080);      // 16
    int*   bsum     = (int*)(ws + 402096);      // 256
    float* den      = ws + 402352;              // 200,000
    int*   count    = (int*)(ws + 602352);      // 50,000
    int*   cursor   = (int*)(ws + 652352);      // 50,000
    int*   row_start= (int*)(ws + 702352);      // 50,001 (+3 pad)
    u16t*  Wfrag    = (u16t*)(ws + 752356);     // 32,768 bf16 (16,384 f32)

    // d_out: f32 out [50000,128] then f32 alpha [E,4]
    float* outp   = (float*)d_out;              // 6,400,000 f32
    float* alphap = (float*)d_out + 6400000;    // 6,400,000 f32
    // scratch parked inside the alpha region until k_alpha overwrites it:
    u16t*         htail = (u16t*)alphap;                       // 6.4M bf16
    unsigned int* cpack = (unsigned int*)(alphap + 3200000);   // 1.6M u32

    (void)hipMemsetAsync(count, 0, NNODE * sizeof(int), stream);

    k_detect<<<1, 128, 0, stream>>>(el, ety, flag);
    k_prep<<<1, 256, 0, stream>>>(W, We, emb, al, ar, ae, wl, wr, heg);
    k_prepw<<<128, 256, 0, stream>>>(W, Wfrag);
    k_fuseA<<<31250, 256, 0, stream>>>(head, tail, wl, wr, el, flag, count, hl, hr);
    k_scan1<<<SCAN_BLOCKS, 256, 0, stream>>>(count, bsum);
    k_scan2<<<1, 256, 0, stream>>>(bsum, row_start);
    k_scan3<<<SCAN_BLOCKS, 256, 0, stream>>>(count, bsum, row_start, cursor);
    k_fuseB<<<9375, 256, 0, stream>>>(tail, Wfrag, htail, el, ety, flag, cursor, cpack);
    k_agg<<<NNODE / 4, 256, 0, stream>>>(row_start, cpack, hl, hr, heg, htail,
                                         den, (float2*)outp);
    k_alpha<<<NEDGE / 256, 256, 0, stream>>>(el, ety, flag, hl, hr, heg, den, alphap);
}

// Round 10
// 380.421 us; speedup vs baseline: 3.1602x; 1.3278x over previous
//
#include <hip/hip_runtime.h>
#include <hip/hip_bf16.h>
#include <string.h>

#define NNODE 50000
#define NEDGE 1600000
#define INF   256
#define NH    4
#define EF    64
#define NET   5

#define NBUCK 782     // bucket = hi>>6 (64 nodes each); 50000/64 -> 0..781
#define BCAP  2560    // per-bucket capacity; mean 2048, sd ~45 -> 11 sigma
#define PBLK  391     // partition blocks, 4096 edges each (391*4096 >= E)

typedef unsigned short u16t;
typedef __attribute__((ext_vector_type(8))) short short8;
typedef __attribute__((ext_vector_type(4))) float f32x4;

__device__ __forceinline__ float b2f(u16t u) {
    union { unsigned int i; float f; } v; v.i = ((unsigned int)u) << 16; return v.f;
}
__device__ __forceinline__ u16t f2b(float f) {
    __hip_bfloat16 h = __float2bfloat16(f);
    u16t u; memcpy(&u, &h, 2); return u;
}

// ---------------------------------------------------------------------------
__global__ void k_detect(const int* __restrict__ el, const int* __restrict__ ety,
                         int* __restrict__ flag) {
    int tid = threadIdx.x;
    int w = tid >> 6, lane = tid & 63;
    const int* p = (w == 0) ? el : ety;
    int x = p[2 * lane + 1];
    unsigned long long b = __ballot(x != 0);
    if (lane == 0) flag[w] = (b == 0ULL) ? 1 : 0;
}

// ---------------------------------------------------------------------------
__global__ void k_prep(const float* __restrict__ W, const float* __restrict__ We,
                       const float* __restrict__ emb, const float* __restrict__ al,
                       const float* __restrict__ ar, const float* __restrict__ ae,
                       float* __restrict__ wl, float* __restrict__ wr,
                       float* __restrict__ he) {
    __shared__ float wes[EF * NH];
    int tid = threadIdx.x;
    {
        int k = tid;
        for (int h = 0; h < NH; h++) {
            float accl = 0.f, accr = 0.f;
            for (int d = 0; d < 32; d++) {
                float w = W[k * 128 + h * 32 + d];
                accl += w * al[h * 32 + d];
                accr += w * ar[h * 32 + d];
            }
            wl[k * NH + h] = accl;
            wr[k * NH + h] = accr;
        }
    }
    if (tid < EF) {
        int k = tid;
        for (int h = 0; h < NH; h++) {
            float s = 0.f;
            for (int d = 0; d < EF; d++)
                s += We[k * (NH * EF) + h * EF + d] * ae[h * EF + d];
            wes[k * NH + h] = s;
        }
    }
    __syncthreads();
    if (tid < NET * NH) {
        int t = tid / NH, h = tid % NH;
        float s = 0.f;
        for (int k = 0; k < EF; k++)
            s += emb[t * EF + k] * wes[k * NH + h];
        he[tid] = s;
    }
}

// ---------------------------------------------------------------------------
__global__ void k_prepw(const float* __restrict__ W, u16t* __restrict__ Wfrag) {
    int idx = blockIdx.x * 256 + threadIdx.x;  // 0..32767
    int j    = idx & 7;
    int lane = (idx >> 3) & 63;
    int ks   = (idx >> 9) & 7;
    int tile = idx >> 12;
    int n = tile * 16 + (lane & 15);
    int k = ks * 32 + (lane >> 4) * 8 + j;
    Wfrag[idx] = f2b(W[k * 128 + n]);
}

// ---------------------------------------------------------------------------
// k_fuseA: [0,12500) rowdot(head->hl); [12500,25000) rowdot(tail->hr);
// [25000,25391) bucket-partition of edges with LDS staging.
// record = ti | (hi&63)<<16 | ty<<22 ; bucket = hi>>6.
// ---------------------------------------------------------------------------
__global__ void k_fuseA(const float* __restrict__ head, const float* __restrict__ tail,
                        const float* __restrict__ wl, const float* __restrict__ wr,
                        const int* __restrict__ el, const int* __restrict__ ety,
                        const int* __restrict__ flag, int* __restrict__ cursor,
                        unsigned int* __restrict__ bucketbuf,
                        float* __restrict__ hl, float* __restrict__ hr) {
    __shared__ float w[INF * NH];
    __shared__ unsigned int srec[4096];
    __shared__ u16t sbuck[4096];
    __shared__ int hist[784];
    __shared__ int loff[784];
    __shared__ int gb[784];
    __shared__ int psum[256];
    int b = blockIdx.x;
    int tid = threadIdx.x;
    if (b < 25000) {
        int ishead = (b < 12500);
        const float* X  = ishead ? head : tail;
        const float* wv = ishead ? wl : wr;
        float* o        = ishead ? hl : hr;
        int bb          = ishead ? b : b - 12500;
        ((float4*)w)[tid] = ((const float4*)wv)[tid];
        __syncthreads();
        int wave = tid >> 6, lane = tid & 63;
        int row = bb * 4 + wave;
        float4 xv = *(const float4*)(X + (size_t)row * INF + lane * 4);
        float xs[4] = {xv.x, xv.y, xv.z, xv.w};
        float4 acc = {0.f, 0.f, 0.f, 0.f};
#pragma unroll
        for (int j = 0; j < 4; j++) {
            float xf = xs[j];
            float4 wvv = ((float4*)w)[lane * 4 + j];
            acc.x += xf * wvv.x; acc.y += xf * wvv.y;
            acc.z += xf * wvv.z; acc.w += xf * wvv.w;
        }
#pragma unroll
        for (int off = 32; off > 0; off >>= 1) {
            acc.x += __shfl_xor(acc.x, off);
            acc.y += __shfl_xor(acc.y, off);
            acc.z += __shfl_xor(acc.z, off);
            acc.w += __shfl_xor(acc.w, off);
        }
        if (lane == 0) ((float4*)o)[row] = acc;
    } else {
        int p = b - 25000;           // 0..390
        int base = p * 4096;
        int wf = flag[0], wt = flag[1];
        for (int i = tid; i < 784; i += 256) hist[i] = 0;
        __syncthreads();
        unsigned int rec[16];
        unsigned int br[16];
#pragma unroll
        for (int i = 0; i < 16; i++) {
            int e = base + i * 256 + tid;
            br[i] = 0xffffffffu;
            rec[i] = 0;
            if (e < NEDGE) {
                int hi = wf ? el[2 * (long long)e]           : el[e];
                int ti = wf ? el[2 * ((long long)NEDGE + e)] : el[NEDGE + e];
                int ty = wt ? ety[2 * (long long)e]          : ety[e];
                int bk = hi >> 6;
                int r = atomicAdd(&hist[bk], 1);
                rec[i] = (unsigned)ti | ((unsigned)(hi & 63) << 16) | ((unsigned)ty << 22);
                br[i]  = (unsigned)bk | ((unsigned)r << 16);
            }
        }
        __syncthreads();
        int s4[4]; int tsum = 0;
        if (tid < 196) {
#pragma unroll
            for (int j = 0; j < 4; j++) { s4[j] = hist[4 * tid + j]; tsum += s4[j]; }
        }
        psum[tid] = (tid < 196) ? tsum : 0;
        __syncthreads();
        for (int off = 1; off < 256; off <<= 1) {
            int v = (tid >= off) ? psum[tid - off] : 0;
            __syncthreads();
            psum[tid] += v;
            __syncthreads();
        }
        if (tid < 196) {
            int run = tid ? psum[tid - 1] : 0;
#pragma unroll
            for (int j = 0; j < 4; j++) {
                int bk = 4 * tid + j;
                loff[bk] = run;
                if (s4[j] > 0) gb[bk] = atomicAdd(&cursor[bk], s4[j]);
                run += s4[j];
            }
        }
        __syncthreads();
#pragma unroll
        for (int i = 0; i < 16; i++) {
            if (br[i] != 0xffffffffu) {
                int bk = br[i] & 0xffff;
                int r  = br[i] >> 16;
                int slot = loff[bk] + r;
                srec[slot] = rec[i];
                sbuck[slot] = (u16t)bk;
            }
        }
        __syncthreads();
        int tot = psum[255];
        for (int i = tid; i < tot; i += 256) {
            int bk = sbuck[i];
            int pos = gb[bk] + (i - loff[bk]);
            if (pos < BCAP) bucketbuf[(size_t)bk * BCAP + pos] = srec[i];
        }
    }
}

// ---------------------------------------------------------------------------
__global__ void k_bscan(const int* __restrict__ cursor, int* __restrict__ bstart,
                        int* __restrict__ row_start) {
    __shared__ int psum[256];
    int tid = threadIdx.x;
    int s4[4]; int tsum = 0;
    if (tid < 196) {
#pragma unroll
        for (int j = 0; j < 4; j++) {
            int bk = 4 * tid + j;
            s4[j] = (bk < NBUCK) ? cursor[bk] : 0;
            tsum += s4[j];
        }
    }
    psum[tid] = (tid < 196) ? tsum : 0;
    __syncthreads();
    for (int off = 1; off < 256; off <<= 1) {
        int v = (tid >= off) ? psum[tid - off] : 0;
        __syncthreads();
        psum[tid] += v;
        __syncthreads();
    }
    if (tid < 196) {
        int run = tid ? psum[tid - 1] : 0;
#pragma unroll
        for (int j = 0; j < 4; j++) {
            int bk = 4 * tid + j;
            if (bk < NBUCK) bstart[bk] = run;
            run += s4[j];
        }
    }
    if (tid == 255) {
        bstart[NBUCK] = psum[255];
        row_start[NNODE] = psum[255];
    }
}

// ---------------------------------------------------------------------------
// k_fuseB: [0,3125) MFMA gemm; [3125,3907) per-bucket LDS counting-sort ->
// cpack runs + row_start, coalesced, zero per-edge global atomics.
// ---------------------------------------------------------------------------
__global__ void k_fuseB(const float* __restrict__ X, const u16t* __restrict__ Wfrag,
                        u16t* __restrict__ H, const unsigned int* __restrict__ bucketbuf,
                        const int* __restrict__ cursor, const int* __restrict__ bstart,
                        unsigned int* __restrict__ cpack, int* __restrict__ row_start) {
    __shared__ __attribute__((aligned(16))) u16t alds[16 * 264];
    __shared__ unsigned int lrec[BCAP];
    __shared__ unsigned int lord[BCAP];
    __shared__ int cnt[64];
    __shared__ int sc[64];
    int b = blockIdx.x;
    int tid = threadIdx.x;
    if (b < 3125) {
        int rowbase = b * 16;
        for (int i = tid; i < 1024; i += 256) {
            int row = i >> 6;
            int kc = (i & 63) * 4;
            float4 v = *(const float4*)(X + (size_t)(rowbase + row) * INF + kc);
            u16t* d = alds + row * 264 + kc;
            d[0] = f2b(v.x); d[1] = f2b(v.y); d[2] = f2b(v.z); d[3] = f2b(v.w);
        }
        __syncthreads();
        int wave = tid >> 6, lane = tid & 63;
        int m = lane & 15, quad = lane >> 4;
        int t0 = wave * 2, t1 = t0 + 1;
        f32x4 acc0 = {0.f, 0.f, 0.f, 0.f};
        f32x4 acc1 = {0.f, 0.f, 0.f, 0.f};
#pragma unroll
        for (int ks = 0; ks < 8; ks++) {
            short8 a  = *(const short8*)(alds + m * 264 + ks * 32 + quad * 8);
            short8 b0 = *(const short8*)(Wfrag + (((t0 * 8 + ks) * 64 + lane) << 3));
            short8 b1 = *(const short8*)(Wfrag + (((t1 * 8 + ks) * 64 + lane) << 3));
            acc0 = __builtin_amdgcn_mfma_f32_16x16x32_bf16(a, b0, acc0, 0, 0, 0);
            acc1 = __builtin_amdgcn_mfma_f32_16x16x32_bf16(a, b1, acc1, 0, 0, 0);
        }
        u16t* Hp = H + (size_t)rowbase * 128;
#pragma unroll
        for (int r = 0; r < 4; r++) {
            int row = quad * 4 + r;
            Hp[(size_t)row * 128 + t0 * 16 + m] = f2b(acc0[r]);
            Hp[(size_t)row * 128 + t1 * 16 + m] = f2b(acc1[r]);
        }
    } else {
        int q = b - 3125;                 // bucket 0..781
        int nrec = cursor[q];
        if (nrec > BCAP) nrec = BCAP;
        int bs = bstart[q];
        for (int i = tid; i < nrec; i += 256)
            lrec[i] = bucketbuf[(size_t)q * BCAP + i];
        if (tid < 64) cnt[tid] = 0;
        __syncthreads();
        unsigned int myr[10];
        int k2 = 0;
        for (int i = tid; i < nrec; i += 256) {
            int n = (lrec[i] >> 16) & 63;
            myr[k2++] = atomicAdd(&cnt[n], 1);
        }
        __syncthreads();
        if (tid < 64) sc[tid] = cnt[tid];
        __syncthreads();
        for (int off = 1; off < 64; off <<= 1) {
            int v = (tid >= off && tid < 64) ? sc[tid - off] : 0;
            __syncthreads();
            if (tid < 64) sc[tid] += v;
            __syncthreads();
        }
        k2 = 0;
        for (int i = tid; i < nrec; i += 256) {
            unsigned int rc = lrec[i];
            int n  = (rc >> 16) & 63;
            int ti = rc & 0xffff;
            int ty = rc >> 22;
            int pos = (sc[n] - cnt[n]) + (int)myr[k2++];
            lord[pos] = ((unsigned)ty << 16) | (unsigned)ti;
        }
        __syncthreads();
        for (int i = tid; i < nrec; i += 256)
            cpack[bs + i] = lord[i];
        if (tid < 64) {
            int node = q * 64 + tid;
            if (node < NNODE) row_start[node] = bs + (sc[tid] - cnt[tid]);
        }
    }
}

// ---------------------------------------------------------------------------
__global__ void k_agg(const int* __restrict__ rs, const unsigned int* __restrict__ cpack,
                      const float* __restrict__ hl, const float* __restrict__ hr,
                      const float* __restrict__ heg, const u16t* __restrict__ ht,
                      float* __restrict__ den, float2* __restrict__ out) {
    __shared__ float hes[NET * NH];
    int tid = threadIdx.x;
    if (tid < NET * NH) hes[tid] = heg[tid];
    __syncthreads();
    int wave = tid >> 6, lane = tid & 63;
    int node = blockIdx.x * 4 + wave;
    int start = rs[node], end = rs[node + 1];
    int h = lane >> 4;
    float hlv = hl[node * 4 + h];
    float a0 = 0.f, a1 = 0.f, s = 0.f;
    int j = start;
    for (; j + 4 <= end; j += 4) {
        unsigned c0 = cpack[j], c1 = cpack[j + 1], c2 = cpack[j + 2], c3 = cpack[j + 3];
        int t0 = c0 & 0xffff, t1 = c1 & 0xffff, t2 = c2 & 0xffff, t3 = c3 & 0xffff;
        float r0 = hr[t0 * 4 + h], r1 = hr[t1 * 4 + h];
        float r2 = hr[t2 * 4 + h], r3 = hr[t3 * 4 + h];
        unsigned v0 = *(const unsigned*)(ht + (size_t)t0 * 128 + lane * 2);
        unsigned v1 = *(const unsigned*)(ht + (size_t)t1 * 128 + lane * 2);
        unsigned v2 = *(const unsigned*)(ht + (size_t)t2 * 128 + lane * 2);
        unsigned v3 = *(const unsigned*)(ht + (size_t)t3 * 128 + lane * 2);
        float x0 = hlv + r0 + hes[(c0 >> 16) * 4 + h];
        float x1 = hlv + r1 + hes[(c1 >> 16) * 4 + h];
        float x2 = hlv + r2 + hes[(c2 >> 16) * 4 + h];
        float x3 = hlv + r3 + hes[(c3 >> 16) * 4 + h];
        x0 = x0 > 0.f ? x0 : 0.2f * x0;
        x1 = x1 > 0.f ? x1 : 0.2f * x1;
        x2 = x2 > 0.f ? x2 : 0.2f * x2;
        x3 = x3 > 0.f ? x3 : 0.2f * x3;
        float e0 = __expf(x0), e1 = __expf(x1), e2 = __expf(x2), e3 = __expf(x3);
        a0 += e0 * b2f((u16t)(v0 & 0xffff)) + e1 * b2f((u16t)(v1 & 0xffff))
            + e2 * b2f((u16t)(v2 & 0xffff)) + e3 * b2f((u16t)(v3 & 0xffff));
        a1 += e0 * b2f((u16t)(v0 >> 16)) + e1 * b2f((u16t)(v1 >> 16))
            + e2 * b2f((u16t)(v2 >> 16)) + e3 * b2f((u16t)(v3 >> 16));
        s  += e0 + e1 + e2 + e3;
    }
    for (; j < end; j++) {
        unsigned cp = cpack[j];
        int ti = cp & 0xffff;
        int ty = cp >> 16;
        float att = hlv + hr[ti * 4 + h] + hes[ty * 4 + h];
        att = att > 0.f ? att : 0.2f * att;
        float exv = __expf(att);
        unsigned int hv = *(const unsigned*)(ht + (size_t)ti * 128 + lane * 2);
        a0 += exv * b2f((u16t)(hv & 0xffff));
        a1 += exv * b2f((u16t)(hv >> 16));
        s  += exv;
    }
    if ((lane & 15) == 0) den[node * 4 + h] = s;
    float o0 = 0.f, o1 = 0.f;
    if (s > 0.f) { o0 = a0 / s; o1 = a1 / s; }
    o0 = o0 > 0.f ? o0 : expm1f(o0);
    o1 = o1 > 0.f ? o1 : expm1f(o1);
    float2 ov = {o0, o1};
    out[(size_t)node * 64 + lane] = ov;
}

// ---------------------------------------------------------------------------
__global__ void k_alpha(const int* __restrict__ el, const int* __restrict__ ety,
                        const int* __restrict__ flag,
                        const float* __restrict__ hl, const float* __restrict__ hr,
                        const float* __restrict__ heg, const float* __restrict__ den,
                        float* __restrict__ alpha) {
    __shared__ float hes[NET * NH];
    int tid = threadIdx.x;
    if (tid < NET * NH) hes[tid] = heg[tid];
    __syncthreads();
    int wf = flag[0], wt = flag[1];
    int e = blockIdx.x * 256 + tid;
    int hi = wf ? el[2 * (long long)e]           : el[e];
    int ti = wf ? el[2 * ((long long)NEDGE + e)] : el[NEDGE + e];
    int ty = wt ? ety[2 * (long long)e]          : ety[e];
    float4 l = ((const float4*)hl)[hi];
    float4 r = ((const float4*)hr)[ti];
    float4 d = ((const float4*)den)[hi];
    float v0 = l.x + r.x + hes[ty * 4 + 0];
    float v1 = l.y + r.y + hes[ty * 4 + 1];
    float v2 = l.z + r.z + hes[ty * 4 + 2];
    float v3 = l.w + r.w + hes[ty * 4 + 3];
    v0 = v0 > 0.f ? v0 : 0.2f * v0;
    v1 = v1 > 0.f ? v1 : 0.2f * v1;
    v2 = v2 > 0.f ? v2 : 0.2f * v2;
    v3 = v3 > 0.f ? v3 : 0.2f * v3;
    float4 o;
    o.x = d.x > 0.f ? __expf(v0) / d.x : 0.f;
    o.y = d.y > 0.f ? __expf(v1) / d.y : 0.f;
    o.z = d.z > 0.f ? __expf(v2) / d.z : 0.f;
    o.w = d.w > 0.f ? __expf(v3) / d.w : 0.f;
    ((float4*)alpha)[e] = o;
}

// ---------------------------------------------------------------------------
extern "C" void kernel_launch(void* const* d_in, const int* in_sizes, int n_in,
                              void* d_out, int out_size, void* d_ws, size_t ws_size,
                              hipStream_t stream) {
    const float* head = (const float*)d_in[0];
    const float* tail = (const float*)d_in[1];
    const float* W    = (const float*)d_in[2];
    const float* We   = (const float*)d_in[3];
    const float* emb  = (const float*)d_in[4];
    const float* al   = (const float*)d_in[5];
    const float* ar   = (const float*)d_in[6];
    const float* ae   = (const float*)d_in[7];
    const int*   el   = (const int*)d_in[8];
    const int*   ety  = (const int*)d_in[9];

    float* ws = (float*)d_ws;
    // ws layout (f32-slot offsets), ~2.7 MiB total
    float* hl       = ws;                       // 200,000
    float* hr       = ws + 200000;              // 200,000
    float* wl       = ws + 400000;              // 1,024
    float* wr       = ws + 401024;              // 1,024
    float* heg      = ws + 402048;              // 32
    int*   flag     = (int*)(ws + 402080);      // 16
    int*   bstart   = (int*)(ws + 402096);      // 784
    int*   cursor   = (int*)(ws + 402880);      // 784
    float* den      = ws + 403664;              // 200,000
    int*   row_start= (int*)(ws + 603664);      // 50,001 (+3 pad)
    u16t*  Wfrag    = (u16t*)(ws + 653668);     // 32,768 bf16 (16,384 f32)

    // d_out: f32 out [50000,128] then f32 alpha [E,4]
    float* outp   = (float*)d_out;              // 6,400,000 f32
    float* alphap = (float*)d_out + 6400000;    // 6,400,000 f32
    // scratch in alpha region until k_alpha overwrites: htail + cpack
    u16t*         htail = (u16t*)alphap;                       // 6.4M bf16
    unsigned int* cpack = (unsigned int*)(alphap + 3200000);   // 1.6M u32
    // bucket buffer in out region (consumed by k_fuseB before k_agg writes out)
    unsigned int* bucketbuf = (unsigned int*)outp;             // 782*2560 u32 = 8 MB

    (void)hipMemsetAsync(cursor, 0, NBUCK * sizeof(int), stream);

    k_detect<<<1, 128, 0, stream>>>(el, ety, flag);
    k_prep<<<1, 256, 0, stream>>>(W, We, emb, al, ar, ae, wl, wr, heg);
    k_prepw<<<128, 256, 0, stream>>>(W, Wfrag);
    k_fuseA<<<25000 + PBLK, 256, 0, stream>>>(head, tail, wl, wr, el, ety, flag,
                                              cursor, bucketbuf, hl, hr);
    k_bscan<<<1, 256, 0, stream>>>(cursor, bstart, row_start);
    k_fuseB<<<3125 + NBUCK, 256, 0, stream>>>(tail, Wfrag, htail, bucketbuf,
                                              cursor, bstart, cpack, row_start);
    k_agg<<<NNODE / 4, 256, 0, stream>>>(row_start, cpack, hl, hr, heg, htail,
                                         den, (float2*)outp);
    k_alpha<<<NEDGE / 256, 256, 0, stream>>>(el, ety, flag, hl, hr, heg, den, alphap);
}